// Round 1
// baseline (602.750 us; speedup 1.0000x reference)
//
#include <hip/hip_runtime.h>
#include <stdint.h>

typedef __bf16 bf16;
typedef __bf16 bf16x8 __attribute__((ext_vector_type(8)));
typedef float f32x4 __attribute__((ext_vector_type(4)));

// ---------------- async global->LDS (16B per lane) ----------------
static __device__ __forceinline__ void async16(const void* g, void* l) {
  __builtin_amdgcn_global_load_lds(
      (__attribute__((address_space(1))) void*)g,
      (__attribute__((address_space(3))) void*)l, 16, 0, 0);
}

// ---------------- trig tables ----------------
// Ttrig[1024][512]: row j'=2*jj+p, Ttrig[j'][d] = p? sin(2*pi*d*jj/512) : cos(...)
__global__ void __launch_bounds__(256) gen_ttrig(bf16* __restrict__ T) {
  int idx = blockIdx.x * 256 + threadIdx.x;   // 1024*512
  int d = idx & 511, jp = idx >> 9;
  int jj = jp >> 1, p = jp & 1;
  int t = (d * jj) & 511;                      // exact mod (pow2 period)
  float ang = (float)t * (6.283185307179586f / 512.0f);
  T[idx] = (bf16)(p ? sinf(ang) : cosf(ang));
}

// Atrig[2048][4096]: Atrig[k1][k] = k<2048 ? cos(2*pi*k1*k/2048) : -sin(2*pi*k1*(k-2048)/2048)
__global__ void __launch_bounds__(256) gen_atrig(bf16* __restrict__ T) {
  int idx = blockIdx.x * 256 + threadIdx.x;   // 2048*4096
  int k = idx & 4095, k1 = idx >> 12;
  int p = k >> 11, s = k & 2047;
  int t = (k1 * s) & 2047;
  float ang = (float)t * (6.283185307179586f / 2048.0f);
  float v = p ? -sinf(ang) : cosf(ang);
  T[idx] = (bf16)v;
}

__global__ void __launch_bounds__(256) cast_f2b(const float* __restrict__ in,
                                                bf16* __restrict__ out, int n) {
  int i = blockIdx.x * 256 + threadIdx.x;
  if (i < n) out[i] = (bf16)in[i];
}

// ---------------- tiled transpose: in [R x C] (z slices) -> out bf16 [C x R] ----------------
template <typename TI>
__global__ void __launch_bounds__(256) transpose_to_bf16(
    const TI* __restrict__ in, bf16* __restrict__ out, int R, int C, long inz, long outz) {
  __shared__ bf16 tile[32][33];
  int z = blockIdx.z;
  in += inz * z; out += outz * z;
  int c0 = blockIdx.x * 32, r0 = blockIdx.y * 32;
  int tx = threadIdx.x & 31, ty = threadIdx.x >> 5;   // 32 x 8
#pragma unroll
  for (int i = 0; i < 32; i += 8)
    tile[ty + i][tx] = (bf16)(float)in[(long)(r0 + ty + i) * C + (c0 + tx)];
  __syncthreads();
#pragma unroll
  for (int i = 0; i < 32; i += 8)
    out[(long)(c0 + ty + i) * R + (r0 + tx)] = tile[tx][ty + i];
}

// ---------------- softmax over head axis (H=4) on [B,4,S,D] bf16, in place ----------------
__global__ void __launch_bounds__(256) softmax_heads(bf16* __restrict__ x) {
  int idx = blockIdx.x * 256 + threadIdx.x;   // < 4*2048*512
  int b = idx >> 20;                          // S*D = 2^20
  long base = (long)b * (3l << 20) + idx;     // = b*4M + (idx - b*1M)
  const long HS = 1l << 20;
  float v0 = (float)x[base];
  float v1 = (float)x[base + HS];
  float v2 = (float)x[base + 2 * HS];
  float v3 = (float)x[base + 3 * HS];
  float m = fmaxf(fmaxf(v0, v1), fmaxf(v2, v3));
  float e0 = expf(v0 - m), e1 = expf(v1 - m), e2 = expf(v2 - m), e3 = expf(v3 - m);
  float rs = 1.0f / (e0 + e1 + e2 + e3);
  x[base] = (bf16)(e0 * rs);
  x[base + HS] = (bf16)(e1 * rs);
  x[base + 2 * HS] = (bf16)(e2 * rs);
  x[base + 3 * HS] = (bf16)(e3 * rs);
}

// ---------------- LayerNorm over D=512: out = g*(A+B - mu)*rstd + be ----------------
template <int WRITE_BF16, int WRITE_F32>
__global__ void __launch_bounds__(256) ln_kernel(
    const float* __restrict__ A, const float* __restrict__ Bv,
    const float* __restrict__ g, const float* __restrict__ be,
    bf16* __restrict__ outb, float* __restrict__ outf) {
  const int row = blockIdx.x, t = threadIdx.x;
  const long base = (long)row * 512;
  float v0 = A[base + t] + Bv[base + t];
  float v1 = A[base + t + 256] + Bv[base + t + 256];
  float s = v0 + v1, q = v0 * v0 + v1 * v1;
#pragma unroll
  for (int off = 32; off > 0; off >>= 1) {
    s += __shfl_down(s, off);
    q += __shfl_down(q, off);
  }
  __shared__ float red[8];
  const int wv = t >> 6, ln = t & 63;
  if (ln == 0) { red[wv] = s; red[wv + 4] = q; }
  __syncthreads();
  float S = red[0] + red[1] + red[2] + red[3];
  float Q = red[4] + red[5] + red[6] + red[7];
  float mu = S * (1.0f / 512.0f);
  float var = Q * (1.0f / 512.0f) - mu * mu;
  float rstd = rsqrtf(var + 1e-5f);
  float o0 = g[t] * (v0 - mu) * rstd + be[t];
  float o1 = g[t + 256] * (v1 - mu) * rstd + be[t + 256];
  if (WRITE_BF16) { outb[base + t] = (bf16)o0; outb[base + t + 256] = (bf16)o1; }
  if (WRITE_F32)  { outf[base + t] = o0; outf[base + t + 256] = o1; }
}

// ---------------- GEMM: C[M,N] = A[M,K] * Bt[N,K]^T  (both row-major, K contiguous) --------
// m97-style: 128x128 tile, BK=64, 256 thr, global_load_lds w16, XOR bank swizzle,
// 4x4 mfma_f32_16x16x32_bf16 per wave. ADDR_MODE: 0 plain (sCz*z), 1 QKV scatter (z=head),
// 2 attn-cat scatter (z=b*4+h, col -> col*4+h).
template <int ADDR_MODE, int HAS_BIAS, int DO_SELU, int F32OUT>
__global__ void __launch_bounds__(256, 2) gemm_bt(
    const bf16* __restrict__ A, const bf16* __restrict__ Bt,
    const float* __restrict__ bias, void* __restrict__ Cout,
    int M, int N, int K, long sAz, long sBz, long sBiasz, long sCz) {
  __shared__ __align__(16) bf16 lA[128 * 64];
  __shared__ __align__(16) bf16 lB[128 * 64];
  const int z = blockIdx.z;
  A  += sAz * z;
  Bt += sBz * z;
  const int m0 = blockIdx.y * 128, n0 = blockIdx.x * 128;
  const int t = threadIdx.x;
  const int lane = t & 63, wave = t >> 6;
  const int srow = t >> 3;             // staging row within 32-row group
  const int pch  = t & 7;              // physical 16B chunk (LDS side: base + lane*16)
  const int lch  = pch ^ (srow & 7);   // logical k-chunk fetched from global (swizzle)
  const bf16* Ag = A  + (long)(m0 + srow) * K + lch * 8;
  const bf16* Bg = Bt + (long)(n0 + srow) * K + lch * 8;
  bf16* lAp = lA + srow * 64 + pch * 8;
  bf16* lBp = lB + srow * 64 + pch * 8;
  const int wm = (wave >> 1) * 64, wn = (wave & 1) * 64;
  const int fr = lane & 15, fq = lane >> 4;

  f32x4 acc[4][4] = {};

  for (int k0 = 0; k0 < K; k0 += 64) {
    __syncthreads();
#pragma unroll
    for (int i = 0; i < 4; ++i) {
      async16(Ag + k0 + (long)(32 * i) * K, lAp + 32 * i * 64);
      async16(Bg + k0 + (long)(32 * i) * K, lBp + 32 * i * 64);
    }
    __syncthreads();   // drains vmcnt(0) -> LDS ready
#pragma unroll
    for (int kk = 0; kk < 2; ++kk) {
      bf16x8 av[4], bfrag[4];
#pragma unroll
      for (int mi = 0; mi < 4; ++mi) {
        int r = wm + mi * 16 + fr;
        int c = (kk * 4 + fq) ^ (r & 7);
        av[mi] = *(const bf16x8*)&lA[r * 64 + c * 8];
      }
#pragma unroll
      for (int ni = 0; ni < 4; ++ni) {
        int r = wn + ni * 16 + fr;
        int c = (kk * 4 + fq) ^ (r & 7);
        bfrag[ni] = *(const bf16x8*)&lB[r * 64 + c * 8];
      }
#pragma unroll
      for (int mi = 0; mi < 4; ++mi)
#pragma unroll
        for (int ni = 0; ni < 4; ++ni)
          acc[mi][ni] = __builtin_amdgcn_mfma_f32_16x16x32_bf16(
              av[mi], bfrag[ni], acc[mi][ni], 0, 0, 0);
    }
  }

  // epilogue: C/D layout col = lane&15, row = (lane>>4)*4 + reg
#pragma unroll
  for (int mi = 0; mi < 4; ++mi) {
#pragma unroll
    for (int ni = 0; ni < 4; ++ni) {
      const int col = n0 + wn + ni * 16 + fr;
      float bias_v = 0.0f;
      if (HAS_BIAS) bias_v = bias[sBiasz * z + col];
#pragma unroll
      for (int r = 0; r < 4; ++r) {
        const int row = m0 + wm + mi * 16 + fq * 4 + r;
        float v = acc[mi][ni][r] + bias_v;
        if (DO_SELU) v = v > 0.0f ? 1.0507009873554805f * v
                                  : 1.7580993408473766f * (expf(v) - 1.0f);
        long addr;
        if (ADDR_MODE == 0) {
          addr = sCz * z + (long)row * N + col;
        } else if (ADDR_MODE == 1) {           // z = head; rows are b*2048+s
          int b = row >> 11, s = row & 2047;
          addr = ((long)((b << 2) + z) * 2048 + s) * 512 + col;
        } else {                               // z = b*4+h; 'b h s d -> b s (d h)'
          int b = z >> 2, h = z & 3;
          addr = ((long)(b * 2048 + row)) * 2048 + col * 4 + h;
        }
        if (F32OUT) ((float*)Cout)[addr] = v;
        else        ((bf16*)Cout)[addr] = (bf16)v;
      }
    }
  }
}

// ---------------- launcher ----------------
extern "C" void kernel_launch(void* const* d_in, const int* in_sizes, int n_in,
                              void* d_out, int out_size, void* d_ws, size_t ws_size,
                              hipStream_t stream) {
  (void)in_sizes; (void)n_in; (void)out_size; (void)ws_size;
  const float* x_enc = (const float*)d_in[0];
  const float* x_dec = (const float*)d_in[1];
  const float* Wq = (const float*)d_in[2];
  const float* bq = (const float*)d_in[3];
  const float* Wk = (const float*)d_in[4];
  const float* bk = (const float*)d_in[5];
  const float* Wv = (const float*)d_in[6];
  const float* bv = (const float*)d_in[7];
  const float* Wo = (const float*)d_in[8];
  const float* bo = (const float*)d_in[9];
  const float* g1 = (const float*)d_in[10];
  const float* be1 = (const float*)d_in[11];
  const float* g2 = (const float*)d_in[12];
  const float* be2 = (const float*)d_in[13];
  const float* W1 = (const float*)d_in[14];
  const float* b1 = (const float*)d_in[15];
  const float* W2 = (const float*)d_in[16];
  const float* b2 = (const float*)d_in[17];
  const float* g3 = (const float*)d_in[18];
  const float* be3 = (const float*)d_in[19];

  char* ws = (char*)d_ws;
  const size_t MB = 1u << 20;
  // aliased regions, peak 237 MiB (aliases are strictly time-disjoint on the stream)
  bf16*  Atrig  = (bf16*) (ws + 0);        // 16 MiB, dead after DFT-S GEMM
  float* xd_f   = (float*)(ws + 0);        // written by LN1
  bf16*  Ttrig  = (bf16*) (ws + 16 * MB);  // 1 MiB
  bf16*  Yt     = (bf16*) (ws + 17 * MB);  // 16 MiB, dead after DFT-S
  float* attn_f = (float*)(ws + 17 * MB);  // written by Wo GEMM, dead after LN2
  float* ff_f   = (float*)(ws + 17 * MB);  // written by W2 GEMM
  float* xf_f   = (float*)(ws + 33 * MB);  // 16 MiB, dead after LN1
  float* x2_f   = (float*)(ws + 33 * MB);  // written by LN2
  bf16*  xd_b   = (bf16*) (ws + 49 * MB);  // 8 MiB
  bf16*  qs     = (bf16*) (ws + 57 * MB);  // 32 MiB
  bf16*  xdec_b = (bf16*) (ws + 57 * MB);  // 8 MiB, dead before qs written
  bf16*  klog   = (bf16*) (ws + 89 * MB);  // 32 MiB, dead after k-transpose
  bf16*  midb   = (bf16*) (ws + 89 * MB);  // written by W1 GEMM
  bf16*  ksT    = (bf16*) (ws + 121 * MB); // 32 MiB, dead after gc GEMM
  bf16*  cat    = (bf16*) (ws + 121 * MB); // written by out GEMM
  bf16*  vtmp   = (bf16*) (ws + 153 * MB); // 32 MiB, dead after v-transpose
  bf16*  gcT    = (bf16*) (ws + 153 * MB); // 8 MiB, written by gc GEMM
  bf16*  vsT    = (bf16*) (ws + 185 * MB); // 32 MiB
  bf16*  xenc_b = (bf16*) (ws + 185 * MB); // 8 MiB, dead before vsT written
  bf16*  x2_b   = (bf16*) (ws + 217 * MB); // 8 MiB
  bf16*  WqT    = (bf16*) (ws + 225 * MB);
  bf16*  WkT    = (bf16*) (ws + 227 * MB);
  bf16*  WvT    = (bf16*) (ws + 229 * MB);
  bf16*  WoT    = (bf16*) (ws + 231 * MB);
  bf16*  W1T    = (bf16*) (ws + 233 * MB);
  bf16*  W2T    = (bf16*) (ws + 235 * MB); // end 237 MiB

  // --- prep: trig tables, bf16 casts, weight transposes (to B^T layouts) ---
  gen_ttrig<<<2048, 256, 0, stream>>>(Ttrig);
  gen_atrig<<<32768, 256, 0, stream>>>(Atrig);
  cast_f2b<<<16384, 256, 0, stream>>>(x_dec, xdec_b, 4194304);
  cast_f2b<<<16384, 256, 0, stream>>>(x_enc, xenc_b, 4194304);
  transpose_to_bf16<float><<<dim3(16, 16, 4), 256, 0, stream>>>(Wq, WqT, 512, 512, 262144L, 262144L);
  transpose_to_bf16<float><<<dim3(16, 16, 4), 256, 0, stream>>>(Wk, WkT, 512, 512, 262144L, 262144L);
  transpose_to_bf16<float><<<dim3(16, 16, 4), 256, 0, stream>>>(Wv, WvT, 512, 512, 262144L, 262144L);
  transpose_to_bf16<float><<<dim3(16, 64, 1), 256, 0, stream>>>(Wo, WoT, 2048, 512, 0L, 0L);
  transpose_to_bf16<float><<<dim3(64, 16, 1), 256, 0, stream>>>(W1, W1T, 512, 2048, 0L, 0L);
  transpose_to_bf16<float><<<dim3(16, 64, 1), 256, 0, stream>>>(W2, W2T, 2048, 512, 0L, 0L);

  // --- Fourier mixing: Yt[b][2*jj+p][s] = (x_dec[b] . C2/S2)[s,jj]  (K=512) ---
  gemm_bt<0, 0, 0, 0><<<dim3(16, 8, 4), 256, 0, stream>>>(
      Ttrig, xdec_b, nullptr, Yt, 1024, 2048, 512, 0L, 1048576L, 0L, 2097152L);
  // xf[b] = [C1 | -S1] (2048x4096) . Ystack[b]  (K=4096), fp32 out
  gemm_bt<0, 0, 0, 1><<<dim3(4, 16, 4), 256, 0, stream>>>(
      Atrig, Yt, nullptr, xf_f, 2048, 512, 4096, 0L, 2097152L, 0L, 1048576L);
  // xd = LN1(x_dec + xf)
  ln_kernel<1, 1><<<8192, 256, 0, stream>>>(x_dec, xf_f, g1, be1, xd_b, xd_f);

  // --- QKV projections (z = head), scatter to [B,H,S,D] ---
  gemm_bt<1, 1, 0, 0><<<dim3(4, 64, 4), 256, 0, stream>>>(
      xd_b, WqT, bq, qs, 8192, 512, 512, 0L, 262144L, 512L, 0L);
  gemm_bt<1, 1, 0, 0><<<dim3(4, 64, 4), 256, 0, stream>>>(
      xenc_b, WkT, bk, klog, 8192, 512, 512, 0L, 262144L, 512L, 0L);
  gemm_bt<1, 1, 0, 0><<<dim3(4, 64, 4), 256, 0, stream>>>(
      xenc_b, WvT, bv, vtmp, 8192, 512, 512, 0L, 262144L, 512L, 0L);
  softmax_heads<<<16384, 256, 0, stream>>>(qs);
  softmax_heads<<<16384, 256, 0, stream>>>(klog);
  // ks, vs -> [B,H,D,S] so gc GEMM has K=s contiguous on both operands
  transpose_to_bf16<bf16><<<dim3(16, 64, 16), 256, 0, stream>>>(klog, ksT, 2048, 512, 1048576L, 1048576L);
  transpose_to_bf16<bf16><<<dim3(16, 64, 16), 256, 0, stream>>>(vtmp, vsT, 2048, 512, 1048576L, 1048576L);
  // gcT[e,d] = sum_s vs[s,e]*ks[s,d]   (z = b*4+h, K=2048)
  gemm_bt<0, 0, 0, 0><<<dim3(4, 4, 16), 256, 0, stream>>>(
      vsT, ksT, nullptr, gcT, 512, 512, 2048, 1048576L, 1048576L, 0L, 262144L);
  // out = qs . gc, scattered to cat[b, s, d*4+h]  (z = b*4+h)
  gemm_bt<2, 0, 0, 0><<<dim3(4, 16, 16), 256, 0, stream>>>(
      qs, gcT, nullptr, cat, 2048, 512, 512, 1048576L, 262144L, 0L, 0L);
  // attn = cat . Wo + bo (fp32 out)
  gemm_bt<0, 1, 0, 1><<<dim3(4, 64, 1), 256, 0, stream>>>(
      cat, WoT, bo, attn_f, 8192, 512, 2048, 0L, 0L, 0L, 0L);
  // x2 = LN2(xd + attn)
  ln_kernel<1, 1><<<8192, 256, 0, stream>>>(xd_f, attn_f, g2, be2, x2_b, x2_f);

  // --- FFN: mid = selu(x2.W1 + b1); ff = mid.W2 + b2; out = LN3(x2 + ff) ---
  gemm_bt<0, 1, 1, 0><<<dim3(16, 64, 1), 256, 0, stream>>>(
      x2_b, W1T, b1, midb, 8192, 2048, 512, 0L, 0L, 0L, 0L);
  gemm_bt<0, 1, 0, 1><<<dim3(4, 64, 1), 256, 0, stream>>>(
      midb, W2T, b2, ff_f, 8192, 512, 2048, 0L, 0L, 0L, 0L);
  ln_kernel<0, 1><<<8192, 256, 0, stream>>>(x2_f, ff_f, g3, be3, nullptr, (float*)d_out);
}

// Round 2
// 516.381 us; speedup vs baseline: 1.1673x; 1.1673x over previous
//
#include <hip/hip_runtime.h>
#include <stdint.h>

typedef __bf16 bf16;
typedef __bf16 bf16x8 __attribute__((ext_vector_type(8)));
typedef float f32x4 __attribute__((ext_vector_type(4)));

// ---------------- async global->LDS (16B per lane) ----------------
static __device__ __forceinline__ void async16(const void* g, void* l) {
  __builtin_amdgcn_global_load_lds(
      (__attribute__((address_space(1))) void*)g,
      (__attribute__((address_space(3))) void*)l, 16, 0, 0);
}

// ---------------- trig tables ----------------
// Ttrig[1024][512]: row j'=2*jj+p, Ttrig[j'][d] = p? sin(2*pi*d*jj/512) : cos(...)
__global__ void __launch_bounds__(256) gen_ttrig(bf16* __restrict__ T) {
  int idx = blockIdx.x * 256 + threadIdx.x;   // 1024*512
  int d = idx & 511, jp = idx >> 9;
  int jj = jp >> 1, p = jp & 1;
  int t = (d * jj) & 511;                      // exact mod (pow2 period)
  float ang = (float)t * (6.283185307179586f / 512.0f);
  T[idx] = (bf16)(p ? sinf(ang) : cosf(ang));
}

// Afold[2048][2048]: k<1025 -> cos(2*pi*k1*k/2048); k>=1025 -> -sin(2*pi*k1*(k-1024)/2048)
__global__ void __launch_bounds__(256) gen_afold(bf16* __restrict__ T) {
  int idx = blockIdx.x * 256 + threadIdx.x;   // 2048*2048
  int k = idx & 2047, k1 = idx >> 11;
  int s = (k < 1025) ? k : (k - 1024);
  int t = (k1 * s) & 2047;
  float ang = (float)t * (6.283185307179586f / 2048.0f);
  float v = (k < 1025) ? cosf(ang) : -sinf(ang);
  T[idx] = (bf16)v;
}

// Fold Yt [4][512][4096] (k = p*2048+s) -> Yf [4][512][2048] using s <-> 2048-s symmetry.
__global__ void __launch_bounds__(256) fold_y(const bf16* __restrict__ Yt,
                                              bf16* __restrict__ Yf) {
  int idx = blockIdx.x * 256 + threadIdx.x;   // 4*512*2048
  int k = idx & 2047;
  int j = (idx >> 11) & 511;
  int b = idx >> 20;
  const bf16* yin = Yt + (long)b * 2097152 + (long)j * 4096;
  float v;
  if (k < 1025) {                 // cos part: Yc[k] (+ mirror)
    if (k == 0) v = (float)yin[0];
    else if (k == 1024) v = (float)yin[1024];
    else v = (float)yin[k] + (float)yin[2048 - k];
  } else {                        // sin part: Ys[s] - Ys[2048-s]
    int s = k - 1024;
    v = (float)yin[2048 + s] - (float)yin[2048 + 2048 - s];
  }
  Yf[(long)b * 1048576 + (long)j * 2048 + k] = (bf16)v;
}

__global__ void __launch_bounds__(256) cast_f2b(const float* __restrict__ in,
                                                bf16* __restrict__ out, int n) {
  int i = blockIdx.x * 256 + threadIdx.x;
  if (i < n) out[i] = (bf16)in[i];
}

// ---------------- all six weight transposes in ONE launch ----------------
// blockIdx.x decode: [0,3072) Wq/Wk/Wv (512x512, z=4 each); [3072,4096) Wo (2048x512,
// row-permuted read: k'=h*512+e reads Wo row e*4+h); [4096,5120) W1 (512x2048);
// [5120,6144) W2 (2048x512).
__global__ void __launch_bounds__(256) wtrans_all(
    const float* __restrict__ Wq, const float* __restrict__ Wk,
    const float* __restrict__ Wv, const float* __restrict__ Wo,
    const float* __restrict__ W1, const float* __restrict__ W2,
    bf16* __restrict__ WqT, bf16* __restrict__ WkT, bf16* __restrict__ WvT,
    bf16* __restrict__ WoT, bf16* __restrict__ W1T, bf16* __restrict__ W2T) {
  __shared__ bf16 tile[32][33];
  int id = blockIdx.x;
  const float* in; bf16* out; int R, C, rt, ct; bool perm = false;
  if (id < 3072) {
    int w = id >> 10, rem = id & 1023, z = rem >> 8, t = rem & 255;
    in = (w == 0 ? Wq : w == 1 ? Wk : Wv) + (long)z * 262144;
    out = (w == 0 ? WqT : w == 1 ? WkT : WvT) + (long)z * 262144;
    R = 512; C = 512; rt = t >> 4; ct = t & 15;
  } else if (id < 4096) {
    int t = id - 3072; in = Wo; out = WoT; R = 2048; C = 512; rt = t >> 4; ct = t & 15; perm = true;
  } else if (id < 5120) {
    int t = id - 4096; in = W1; out = W1T; R = 512; C = 2048; rt = t >> 6; ct = t & 63;
  } else {
    int t = id - 5120; in = W2; out = W2T; R = 2048; C = 512; rt = t >> 4; ct = t & 15;
  }
  int c0 = ct * 32, r0 = rt * 32;
  int tx = threadIdx.x & 31, ty = threadIdx.x >> 5;
#pragma unroll
  for (int i = 0; i < 32; i += 8) {
    int r = r0 + ty + i;
    int rr = perm ? (((r & 511) << 2) | (r >> 9)) : r;  // Wo: k'=h*512+e <- row e*4+h
    tile[ty + i][tx] = (bf16)in[(long)rr * C + (c0 + tx)];
  }
  __syncthreads();
#pragma unroll
  for (int i = 0; i < 32; i += 8)
    out[(long)(c0 + ty + i) * R + (r0 + tx)] = tile[tx][ty + i];
}

// ---------------- softmax over head axis (H=4), two buffers in one launch ----------------
__global__ void __launch_bounds__(256) softmax_heads2(bf16* __restrict__ qbuf,
                                                      bf16* __restrict__ kbuf) {
  int bid = blockIdx.x;
  bf16* x = (bid < 16384) ? qbuf : kbuf;
  int idx = (bid & 16383) * 256 + threadIdx.x;   // < 4*2048*512
  int b = idx >> 20;
  long base = (long)b * (3l << 20) + idx;
  const long HS = 1l << 20;
  float v0 = (float)x[base];
  float v1 = (float)x[base + HS];
  float v2 = (float)x[base + 2 * HS];
  float v3 = (float)x[base + 3 * HS];
  float m = fmaxf(fmaxf(v0, v1), fmaxf(v2, v3));
  float e0 = expf(v0 - m), e1 = expf(v1 - m), e2 = expf(v2 - m), e3 = expf(v3 - m);
  float rs = 1.0f / (e0 + e1 + e2 + e3);
  x[base] = (bf16)(e0 * rs);
  x[base + HS] = (bf16)(e1 * rs);
  x[base + 2 * HS] = (bf16)(e2 * rs);
  x[base + 3 * HS] = (bf16)(e3 * rs);
}

// ---------------- LayerNorm over D=512: out = g*(A+B - mu)*rstd + be ----------------
template <int WRITE_BF16, int WRITE_F32>
__global__ void __launch_bounds__(256) ln_kernel(
    const float* __restrict__ A, const float* __restrict__ Bv,
    const float* __restrict__ g, const float* __restrict__ be,
    bf16* __restrict__ outb, float* __restrict__ outf) {
  const int row = blockIdx.x, t = threadIdx.x;
  const long base = (long)row * 512;
  float v0 = A[base + t] + Bv[base + t];
  float v1 = A[base + t + 256] + Bv[base + t + 256];
  float s = v0 + v1, q = v0 * v0 + v1 * v1;
#pragma unroll
  for (int off = 32; off > 0; off >>= 1) {
    s += __shfl_down(s, off);
    q += __shfl_down(q, off);
  }
  __shared__ float red[8];
  const int wv = t >> 6, ln = t & 63;
  if (ln == 0) { red[wv] = s; red[wv + 4] = q; }
  __syncthreads();
  float S = red[0] + red[1] + red[2] + red[3];
  float Q = red[4] + red[5] + red[6] + red[7];
  float mu = S * (1.0f / 512.0f);
  float var = Q * (1.0f / 512.0f) - mu * mu;
  float rstd = rsqrtf(var + 1e-5f);
  float o0 = g[t] * (v0 - mu) * rstd + be[t];
  float o1 = g[t + 256] * (v1 - mu) * rstd + be[t + 256];
  if (WRITE_BF16) { outb[base + t] = (bf16)o0; outb[base + t + 256] = (bf16)o1; }
  if (WRITE_F32)  { outf[base + t] = o0; outf[base + t + 256] = o1; }
}

// ---------------- GEMM: C[M,N] = A[M,K] * Bt[N,K]^T  (both row-major, K contiguous) -------
// BM=128 fixed; BN in {128,64}. 256 thr, global_load_lds w16, XOR bank swizzle,
// mfma_f32_16x16x32_bf16. ADDR_MODE: 0 plain (sCz*z); 1 QKV scatter to [B,H,S,D] (z=head);
// 2 attn out to cat[b, s, h*512+col] (z=b*4+h, coalesced; Wo rows pre-permuted);
// 3 K/V proj transposed scatter to [B,H,D,S] (z=head, packed 8B stores).
template <int BN, int ADDR_MODE, int HAS_BIAS, int DO_SELU, int F32OUT>
__global__ void __launch_bounds__(256, 2) gemm_bt(
    const bf16* __restrict__ A, const bf16* __restrict__ Bt,
    const float* __restrict__ bias, void* __restrict__ Cout,
    int M, int N, int K, long sAz, long sBz, long sBiasz, long sCz) {
  __shared__ __align__(16) bf16 lA[128 * 64];
  __shared__ __align__(16) bf16 lB[BN * 64];
  const int z = blockIdx.z;
  A  += sAz * z;
  Bt += sBz * z;
  const int m0 = blockIdx.y * 128, n0 = blockIdx.x * BN;
  const int t = threadIdx.x;
  const int lane = t & 63, wave = t >> 6;
  const int srow = t >> 3;             // staging row within 32-row group
  const int pch  = t & 7;              // physical 16B chunk (LDS side: base + lane*16)
  const int lch  = pch ^ (srow & 7);   // logical k-chunk fetched from global (swizzle)
  const bf16* Ag = A  + (long)(m0 + srow) * K + lch * 8;
  const bf16* Bg = Bt + (long)(n0 + srow) * K + lch * 8;
  bf16* lAp = lA + srow * 64 + pch * 8;
  bf16* lBp = lB + srow * 64 + pch * 8;
  constexpr int MI = (BN == 128) ? 4 : 2;
  const int wm = (BN == 128) ? (wave >> 1) * 64 : wave * 32;
  const int wn = (BN == 128) ? (wave & 1) * 64 : 0;
  const int fr = lane & 15, fq = lane >> 4;

  f32x4 acc[MI][4] = {};

  for (int k0 = 0; k0 < K; k0 += 64) {
    __syncthreads();
#pragma unroll
    for (int i = 0; i < 4; ++i)
      async16(Ag + k0 + (long)(32 * i) * K, lAp + 32 * i * 64);
#pragma unroll
    for (int i = 0; i < BN / 32; ++i)
      async16(Bg + k0 + (long)(32 * i) * K, lBp + 32 * i * 64);
    __syncthreads();   // drains vmcnt(0) -> LDS ready
#pragma unroll
    for (int kk = 0; kk < 2; ++kk) {
      bf16x8 av[MI], bfrag[4];
#pragma unroll
      for (int mi = 0; mi < MI; ++mi) {
        int r = wm + mi * 16 + fr;
        int c = (kk * 4 + fq) ^ (r & 7);
        av[mi] = *(const bf16x8*)&lA[r * 64 + c * 8];
      }
#pragma unroll
      for (int ni = 0; ni < 4; ++ni) {
        int r = wn + ni * 16 + fr;
        int c = (kk * 4 + fq) ^ (r & 7);
        bfrag[ni] = *(const bf16x8*)&lB[r * 64 + c * 8];
      }
#pragma unroll
      for (int mi = 0; mi < MI; ++mi)
#pragma unroll
        for (int ni = 0; ni < 4; ++ni)
          acc[mi][ni] = __builtin_amdgcn_mfma_f32_16x16x32_bf16(
              av[mi], bfrag[ni], acc[mi][ni], 0, 0, 0);
    }
  }

  // epilogue: C/D layout col = lane&15, row = (lane>>4)*4 + reg
#pragma unroll
  for (int mi = 0; mi < MI; ++mi) {
#pragma unroll
    for (int ni = 0; ni < 4; ++ni) {
      const int col = n0 + wn + ni * 16 + fr;
      float bias_v = 0.0f;
      if (HAS_BIAS) bias_v = bias[sBiasz * z + col];
      if (ADDR_MODE == 3) {
        const int row0 = m0 + wm + mi * 16 + fq * 4;
        const int b = row0 >> 11, s = row0 & 2047;
        bf16 tmp[4] __attribute__((aligned(8)));
#pragma unroll
        for (int r = 0; r < 4; ++r) tmp[r] = (bf16)(acc[mi][ni][r] + bias_v);
        long addr = ((long)((b << 2) + z) * 512 + col) * 2048 + s;
        *(uint2*)((bf16*)Cout + addr) = *(const uint2*)tmp;
      } else {
#pragma unroll
        for (int r = 0; r < 4; ++r) {
          const int row = m0 + wm + mi * 16 + fq * 4 + r;
          float v = acc[mi][ni][r] + bias_v;
          if (DO_SELU) v = v > 0.0f ? 1.0507009873554805f * v
                                    : 1.7580993408473766f * (expf(v) - 1.0f);
          long addr;
          if (ADDR_MODE == 0) {
            addr = sCz * z + (long)row * N + col;
          } else if (ADDR_MODE == 1) {           // z = head; rows are b*2048+s
            int b = row >> 11, s = row & 2047;
            addr = ((long)((b << 2) + z) * 2048 + s) * 512 + col;
          } else {                               // z = b*4+h; cat[b, s, h*512+col]
            int b = z >> 2, h = z & 3;
            addr = ((long)(b * 2048 + row)) * 2048 + h * 512 + col;
          }
          if (F32OUT) ((float*)Cout)[addr] = v;
          else        ((bf16*)Cout)[addr] = (bf16)v;
        }
      }
    }
  }
}

// ---------------- launcher ----------------
extern "C" void kernel_launch(void* const* d_in, const int* in_sizes, int n_in,
                              void* d_out, int out_size, void* d_ws, size_t ws_size,
                              hipStream_t stream) {
  (void)in_sizes; (void)n_in; (void)out_size; (void)ws_size;
  const float* x_enc = (const float*)d_in[0];
  const float* x_dec = (const float*)d_in[1];
  const float* Wq = (const float*)d_in[2];
  const float* bq = (const float*)d_in[3];
  const float* Wk = (const float*)d_in[4];
  const float* bk = (const float*)d_in[5];
  const float* Wv = (const float*)d_in[6];
  const float* bv = (const float*)d_in[7];
  const float* Wo = (const float*)d_in[8];
  const float* bo = (const float*)d_in[9];
  const float* g1 = (const float*)d_in[10];
  const float* be1 = (const float*)d_in[11];
  const float* g2 = (const float*)d_in[12];
  const float* be2 = (const float*)d_in[13];
  const float* W1 = (const float*)d_in[14];
  const float* b1 = (const float*)d_in[15];
  const float* W2 = (const float*)d_in[16];
  const float* b2 = (const float*)d_in[17];
  const float* g3 = (const float*)d_in[18];
  const float* be3 = (const float*)d_in[19];

  char* ws = (char*)d_ws;
  const size_t MB = 1u << 20;
  // time-disjoint aliases; peak 233 MiB
  bf16*  Yfold  = (bf16*) (ws + 0);        // [0,8)   fold out, dead after A-GEMM
  float* xd_f   = (float*)(ws + 0);        // [0,16)  LN1 out
  bf16*  Ttrig  = (bf16*) (ws + 16 * MB);  // [16,17)
  bf16*  Yt     = (bf16*) (ws + 17 * MB);  // [17,33) dead after fold
  float* attn_f = (float*)(ws + 17 * MB);  // Wo out, dead after LN2
  float* ff_f   = (float*)(ws + 17 * MB);  // W2 out
  float* xf_f   = (float*)(ws + 33 * MB);  // [33,49) dead after LN1
  float* x2_f   = (float*)(ws + 33 * MB);  // LN2 out
  bf16*  xd_b   = (bf16*) (ws + 49 * MB);  // [49,57)
  bf16*  xdec_b = (bf16*) (ws + 57 * MB);  // [57,65) dead after Yt GEMM
  bf16*  qs     = (bf16*) (ws + 57 * MB);  // [57,89) Q-proj out (after LN1)
  bf16*  midb   = (bf16*) (ws + 89 * MB);  // [89,121) W1 out
  bf16*  Afold  = (bf16*) (ws + 121 * MB); // [121,129) dead after A-GEMM
  bf16*  gcT    = (bf16*) (ws + 129 * MB); // [129,137)
  bf16*  vsT    = (bf16*) (ws + 137 * MB); // [137,169)
  bf16*  xenc_b = (bf16*) (ws + 169 * MB); // [169,177)
  bf16*  WqT    = (bf16*) (ws + 177 * MB);
  bf16*  WkT    = (bf16*) (ws + 179 * MB);
  bf16*  WvT    = (bf16*) (ws + 181 * MB);
  bf16*  WoT    = (bf16*) (ws + 183 * MB); // row-permuted (k' = h*512+e)
  bf16*  W1T    = (bf16*) (ws + 185 * MB);
  bf16*  W2T    = (bf16*) (ws + 187 * MB);
  bf16*  ksT    = (bf16*) (ws + 193 * MB); // [193,225) dead after gc GEMM
  bf16*  cat    = (bf16*) (ws + 193 * MB); // out-GEMM out
  bf16*  x2_b   = (bf16*) (ws + 225 * MB); // [225,233)

  // --- prep ---
  gen_ttrig<<<2048, 256, 0, stream>>>(Ttrig);
  gen_afold<<<16384, 256, 0, stream>>>(Afold);
  cast_f2b<<<16384, 256, 0, stream>>>(x_dec, xdec_b, 4194304);
  cast_f2b<<<16384, 256, 0, stream>>>(x_enc, xenc_b, 4194304);
  wtrans_all<<<6144, 256, 0, stream>>>(Wq, Wk, Wv, Wo, W1, W2,
                                       WqT, WkT, WvT, WoT, W1T, W2T);

  // --- Fourier mixing ---
  // Yt[b][2*jj+p][s] = (x_dec[b] . C2/S2)[s,jj]  (K=512)
  gemm_bt<128, 0, 0, 0, 0><<<dim3(16, 8, 4), 256, 0, stream>>>(
      Ttrig, xdec_b, nullptr, Yt, 1024, 2048, 512, 0L, 1048576L, 0L, 2097152L);
  // fold s<->2048-s symmetry: K 4096 -> 2048
  fold_y<<<16384, 256, 0, stream>>>(Yt, Yfold);
  // xf[b] = Afold (2048x2048) . Yfold[b]^T  (K=2048), fp32 out
  gemm_bt<64, 0, 0, 0, 1><<<dim3(8, 16, 4), 256, 0, stream>>>(
      Afold, Yfold, nullptr, xf_f, 2048, 512, 2048, 0L, 1048576L, 0L, 1048576L);
  // xd = LN1(x_dec + xf)
  ln_kernel<1, 1><<<8192, 256, 0, stream>>>(x_dec, xf_f, g1, be1, xd_b, xd_f);

  // --- QKV projections (z = head) ---
  gemm_bt<128, 1, 1, 0, 0><<<dim3(4, 64, 4), 256, 0, stream>>>(
      xd_b, WqT, bq, qs, 8192, 512, 512, 0L, 262144L, 512L, 0L);      // [B,H,S,D]
  gemm_bt<128, 3, 1, 0, 0><<<dim3(4, 64, 4), 256, 0, stream>>>(
      xenc_b, WkT, bk, ksT, 8192, 512, 512, 0L, 262144L, 512L, 0L);   // [B,H,D,S]
  gemm_bt<128, 3, 1, 0, 0><<<dim3(4, 64, 4), 256, 0, stream>>>(
      xenc_b, WvT, bv, vsT, 8192, 512, 512, 0L, 262144L, 512L, 0L);   // [B,H,D,S]
  softmax_heads2<<<32768, 256, 0, stream>>>(qs, ksT);
  // gcT[e,d] = sum_s vs[s,e]*ks[s,d]   (z = b*4+h, K=2048)
  gemm_bt<64, 0, 0, 0, 0><<<dim3(8, 4, 16), 256, 0, stream>>>(
      vsT, ksT, nullptr, gcT, 512, 512, 2048, 1048576L, 1048576L, 0L, 262144L);
  // out = qs . gc -> cat[b, s, h*512+e]  (z = b*4+h, coalesced)
  gemm_bt<128, 2, 0, 0, 0><<<dim3(4, 16, 16), 256, 0, stream>>>(
      qs, gcT, nullptr, cat, 2048, 512, 512, 1048576L, 262144L, 0L, 0L);
  // attn = cat . WoP + bo (fp32 out; WoT rows permuted to match cat layout)
  gemm_bt<64, 0, 1, 0, 1><<<dim3(8, 64, 1), 256, 0, stream>>>(
      cat, WoT, bo, attn_f, 8192, 512, 2048, 0L, 0L, 0L, 0L);
  // x2 = LN2(xd + attn)
  ln_kernel<1, 1><<<8192, 256, 0, stream>>>(xd_f, attn_f, g2, be2, x2_b, x2_f);

  // --- FFN ---
  gemm_bt<128, 0, 1, 1, 0><<<dim3(16, 64, 1), 256, 0, stream>>>(
      x2_b, W1T, b1, midb, 8192, 2048, 512, 0L, 0L, 0L, 0L);
  gemm_bt<64, 0, 1, 0, 1><<<dim3(8, 64, 1), 256, 0, stream>>>(
      midb, W2T, b2, ff_f, 8192, 512, 2048, 0L, 0L, 0L, 0L);
  ln_kernel<0, 1><<<8192, 256, 0, stream>>>(x2_f, ff_f, g3, be3, nullptr, (float*)d_out);
}

// Round 3
// 464.848 us; speedup vs baseline: 1.2967x; 1.1109x over previous
//
#include <hip/hip_runtime.h>
#include <stdint.h>

typedef __bf16 bf16;
typedef __bf16 bf16x8 __attribute__((ext_vector_type(8)));
typedef float f32x4 __attribute__((ext_vector_type(4)));

// ---------------- async global->LDS (16B per lane) ----------------
static __device__ __forceinline__ void async16(const void* g, void* l) {
  __builtin_amdgcn_global_load_lds(
      (__attribute__((address_space(1))) void*)g,
      (__attribute__((address_space(3))) void*)l, 16, 0, 0);
}

// ---------------- trig tables ----------------
__global__ void __launch_bounds__(256) gen_ttrig(bf16* __restrict__ T) {
  int idx = blockIdx.x * 256 + threadIdx.x;   // 1024*512
  int d = idx & 511, jp = idx >> 9;
  int jj = jp >> 1, p = jp & 1;
  int t = (d * jj) & 511;
  float ang = (float)t * (6.283185307179586f / 512.0f);
  T[idx] = (bf16)(p ? sinf(ang) : cosf(ang));
}

// Afold[2048][2048]: k<1025 -> cos(2*pi*k1*k/2048); k>=1025 -> -sin(2*pi*k1*(k-1024)/2048)
__global__ void __launch_bounds__(256) gen_afold(bf16* __restrict__ T) {
  int idx = blockIdx.x * 256 + threadIdx.x;   // 2048*2048
  int k = idx & 2047, k1 = idx >> 11;
  int s = (k < 1025) ? k : (k - 1024);
  int t = (k1 * s) & 2047;
  float ang = (float)t * (6.283185307179586f / 2048.0f);
  float v = (k < 1025) ? cosf(ang) : -sinf(ang);
  T[idx] = (bf16)v;
}

// Fold Yt [4][512][4096] (k = p*2048+s) -> Yf [4][512][2048] via s <-> 2048-s symmetry.
__global__ void __launch_bounds__(256) fold_y(const bf16* __restrict__ Yt,
                                              bf16* __restrict__ Yf) {
  int idx = blockIdx.x * 256 + threadIdx.x;   // 4*512*2048
  int k = idx & 2047;
  int j = (idx >> 11) & 511;
  int b = idx >> 20;
  const bf16* yin = Yt + (long)b * 2097152 + (long)j * 4096;
  float v;
  if (k < 1025) {
    if (k == 0) v = (float)yin[0];
    else if (k == 1024) v = (float)yin[1024];
    else v = (float)yin[k] + (float)yin[2048 - k];
  } else {
    int s = k - 1024;
    v = (float)yin[2048 + s] - (float)yin[2048 + 2048 - s];
  }
  Yf[(long)b * 1048576 + (long)j * 2048 + k] = (bf16)v;
}

__global__ void __launch_bounds__(256) cast_f2b(const float* __restrict__ in,
                                                bf16* __restrict__ out, int n) {
  int i = blockIdx.x * 256 + threadIdx.x;
  if (i < n) out[i] = (bf16)in[i];
}

// ---------------- all six weight transposes in ONE launch ----------------
// kind 0/1: Wq/Wk -> head-interleaved B^T (row n = 4*e+h, col k = din)
// kind 2: Wv per-head transpose; kind 3: Wo row-permuted (k'=h*512+e <- row e*4+h)
// kind 4: W1; kind 5: W2.
__global__ void __launch_bounds__(256) wtrans_all(
    const float* __restrict__ Wq, const float* __restrict__ Wk,
    const float* __restrict__ Wv, const float* __restrict__ Wo,
    const float* __restrict__ W1, const float* __restrict__ W2,
    bf16* __restrict__ BtQ, bf16* __restrict__ BtK, bf16* __restrict__ WvT,
    bf16* __restrict__ WoT, bf16* __restrict__ W1T, bf16* __restrict__ W2T) {
  __shared__ bf16 tile[32][33];
  int id = blockIdx.x;
  int kind = id >> 10, t = id & 1023;
  const float* in; bf16* out; int R, C, rt, ct;
  bool operm = false, iperm = false;
  if (kind == 0)      { in = Wq; out = BtQ; R = 2048; C = 512; rt = t >> 4; ct = t & 15; iperm = true; }
  else if (kind == 1) { in = Wk; out = BtK; R = 2048; C = 512; rt = t >> 4; ct = t & 15; iperm = true; }
  else if (kind == 2) {
    int zz = t >> 8, tt = t & 255;
    in = Wv + (long)zz * 262144; out = WvT + (long)zz * 262144;
    R = 512; C = 512; rt = tt >> 4; ct = tt & 15;
  }
  else if (kind == 3) { in = Wo; out = WoT; R = 2048; C = 512; rt = t >> 4; ct = t & 15; operm = true; }
  else if (kind == 4) { in = W1; out = W1T; R = 512; C = 2048; rt = t >> 6; ct = t & 63; }
  else                { in = W2; out = W2T; R = 2048; C = 512; rt = t >> 4; ct = t & 15; }
  int c0 = ct * 32, r0 = rt * 32;
  int tx = threadIdx.x & 31, ty = threadIdx.x >> 5;
#pragma unroll
  for (int i = 0; i < 32; i += 8) {
    int r = r0 + ty + i;
    int rr = operm ? (((r & 511) << 2) | (r >> 9)) : r;
    tile[ty + i][tx] = (bf16)in[(long)rr * C + (c0 + tx)];
  }
  __syncthreads();
#pragma unroll
  for (int i = 0; i < 32; i += 8) {
    int cc = c0 + ty + i, rr = r0 + tx;
    if (iperm)
      out[((long)(4 * cc + (rr >> 9)) << 9) + (rr & 511)] = tile[tx][ty + i];
    else
      out[(long)cc * R + rr] = tile[tx][ty + i];
  }
}

// ---------------- LayerNorm over D=512: out = g*(A+B - mu)*rstd + be ----------------
template <int WRITE_BF16, int WRITE_F32>
__global__ void __launch_bounds__(256) ln_kernel(
    const float* __restrict__ A, const float* __restrict__ Bv,
    const float* __restrict__ g, const float* __restrict__ be,
    bf16* __restrict__ outb, float* __restrict__ outf) {
  const int row = blockIdx.x, t = threadIdx.x;
  const long base = (long)row * 512;
  float v0 = A[base + t] + Bv[base + t];
  float v1 = A[base + t + 256] + Bv[base + t + 256];
  float s = v0 + v1, q = v0 * v0 + v1 * v1;
#pragma unroll
  for (int off = 32; off > 0; off >>= 1) {
    s += __shfl_down(s, off);
    q += __shfl_down(q, off);
  }
  __shared__ float red[8];
  const int wv = t >> 6, ln = t & 63;
  if (ln == 0) { red[wv] = s; red[wv + 4] = q; }
  __syncthreads();
  float S = red[0] + red[1] + red[2] + red[3];
  float Q = red[4] + red[5] + red[6] + red[7];
  float mu = S * (1.0f / 512.0f);
  float var = Q * (1.0f / 512.0f) - mu * mu;
  float rstd = rsqrtf(var + 1e-5f);
  float o0 = g[t] * (v0 - mu) * rstd + be[t];
  float o1 = g[t + 256] * (v1 - mu) * rstd + be[t + 256];
  if (WRITE_BF16) { outb[base + t] = (bf16)o0; outb[base + t + 256] = (bf16)o1; }
  if (WRITE_F32)  { outf[base + t] = o0; outf[base + t + 256] = o1; }
}

// ---------------- GEMM: C = A[M,K] * Bt[N,K]^T, 1D grid with XCD-group swizzle ---------
// SWIZ: 0 plain (x fastest); 1 group-by-y (all blocks sharing an A row-tile land on one
// XCD: flat_id%8 == y%8; needs gy%8==0); 2 group-by-z (flat_id%8 == z%8; needs gz%8==0).
// gin = blocks per group (gx*gz for SWIZ=1, gx*gy for SWIZ=2).
// ADDR_MODE: 0 plain (sCz*z); 2 attn out to cat[b,s,h*512+col] (z=b*4+h);
// 3 V transposed scatter to [B,H,D,S] (z=head, 8B packed);
// 4 Q head-interleaved (col=4e+h): fused head-softmax, store qs[b,h,s,e];
// 5 K head-interleaved: fused head-softmax, transposed 8B store ksT[b,h,e,s].
template <int BN, int ADDR_MODE, int HAS_BIAS, int DO_SELU, int F32OUT, int SWIZ>
__global__ void __launch_bounds__(256, 2) gemm_bt(
    const bf16* __restrict__ A, const bf16* __restrict__ Bt,
    const float* __restrict__ bias, void* __restrict__ Cout,
    int N, int K, long sAz, long sBz, long sBiasz, long sCz,
    int gx, int gy, int gin) {
  __shared__ __align__(16) bf16 lA[128 * 64];
  __shared__ __align__(16) bf16 lB[BN * 64];
  int x, y, z;
  {
    int id = blockIdx.x;
    if (SWIZ == 0) {
      x = id % gx; int t2 = id / gx; y = t2 % gy; z = t2 / gy;
    } else {
      int xcd = id & 7, r = id >> 3;
      int inner = r % gin, G = xcd + 8 * (r / gin);
      if (SWIZ == 1) { y = G; x = inner % gx; z = inner / gx; }
      else           { z = G; x = inner % gx; y = inner / gx; }
    }
  }
  A  += sAz * z;
  Bt += sBz * z;
  const int m0 = y * 128, n0 = x * BN;
  const int t = threadIdx.x;
  const int lane = t & 63, wave = t >> 6;
  const int srow = t >> 3;
  const int pch  = t & 7;
  const int lch  = pch ^ (srow & 7);   // XOR bank swizzle (global-side)
  const bf16* Ag = A  + (long)(m0 + srow) * K + lch * 8;
  const bf16* Bg = Bt + (long)(n0 + srow) * K + lch * 8;
  bf16* lAp = lA + srow * 64 + pch * 8;
  bf16* lBp = lB + srow * 64 + pch * 8;
  constexpr int MI = (BN == 128) ? 4 : 2;
  const int wm = (BN == 128) ? (wave >> 1) * 64 : wave * 32;
  const int wn = (BN == 128) ? (wave & 1) * 64 : 0;
  const int fr = lane & 15, fq = lane >> 4;

  f32x4 acc[MI][4] = {};

  for (int k0 = 0; k0 < K; k0 += 64) {
    __syncthreads();
#pragma unroll
    for (int i = 0; i < 4; ++i)
      async16(Ag + k0 + (long)(32 * i) * K, lAp + 32 * i * 64);
#pragma unroll
    for (int i = 0; i < BN / 32; ++i)
      async16(Bg + k0 + (long)(32 * i) * K, lBp + 32 * i * 64);
    __syncthreads();
#pragma unroll
    for (int kk = 0; kk < 2; ++kk) {
      bf16x8 av[MI], bfrag[4];
#pragma unroll
      for (int mi = 0; mi < MI; ++mi) {
        int r = wm + mi * 16 + fr;
        int c = (kk * 4 + fq) ^ (r & 7);
        av[mi] = *(const bf16x8*)&lA[r * 64 + c * 8];
      }
#pragma unroll
      for (int ni = 0; ni < 4; ++ni) {
        int r = wn + ni * 16 + fr;
        int c = (kk * 4 + fq) ^ (r & 7);
        bfrag[ni] = *(const bf16x8*)&lB[r * 64 + c * 8];
      }
#pragma unroll
      for (int mi = 0; mi < MI; ++mi)
#pragma unroll
        for (int ni = 0; ni < 4; ++ni)
          acc[mi][ni] = __builtin_amdgcn_mfma_f32_16x16x32_bf16(
              av[mi], bfrag[ni], acc[mi][ni], 0, 0, 0);
    }
  }

  // epilogue: C/D layout col = lane&15, row = (lane>>4)*4 + reg
#pragma unroll
  for (int mi = 0; mi < MI; ++mi) {
#pragma unroll
    for (int ni = 0; ni < 4; ++ni) {
      const int col = n0 + wn + ni * 16 + fr;
      float bias_v = 0.0f;
      if (HAS_BIAS) {
        if (ADDR_MODE == 4 || ADDR_MODE == 5)
          bias_v = bias[(col & 3) * 512 + (col >> 2)];
        else
          bias_v = bias[sBiasz * z + col];
      }
      if (ADDR_MODE == 3) {
        const int row0 = m0 + wm + mi * 16 + fq * 4;
        const int b = row0 >> 11, s = row0 & 2047;
        bf16 tmp[4] __attribute__((aligned(8)));
#pragma unroll
        for (int r = 0; r < 4; ++r) tmp[r] = (bf16)(acc[mi][ni][r] + bias_v);
        long addr = ((long)((b << 2) + z) * 512 + col) * 2048 + s;
        *(uint2*)((bf16*)Cout + addr) = *(const uint2*)tmp;
      } else if (ADDR_MODE == 4 || ADDR_MODE == 5) {
        bf16 tmp[4] __attribute__((aligned(8)));
#pragma unroll
        for (int r = 0; r < 4; ++r) {
          float v = acc[mi][ni][r] + bias_v;
          float mx = fmaxf(v, __shfl_xor(v, 1));
          mx = fmaxf(mx, __shfl_xor(mx, 2));
          float e = expf(v - mx);
          float ssum = e + __shfl_xor(e, 1);
          ssum += __shfl_xor(ssum, 2);
          tmp[r] = (bf16)(e / ssum);
        }
        const int row0 = m0 + wm + mi * 16 + fq * 4;
        const int b = row0 >> 11, s = row0 & 2047;
        const int h = col & 3, eo = col >> 2;
        if (ADDR_MODE == 4) {
          bf16* basep = (bf16*)Cout + ((long)((b << 2) + h) * 2048 + s) * 512 + eo;
#pragma unroll
          for (int r = 0; r < 4; ++r) basep[(long)r * 512] = tmp[r];
        } else {
          *(uint2*)((bf16*)Cout + ((long)((b << 2) + h) * 512 + eo) * 2048 + s) =
              *(const uint2*)tmp;
        }
      } else {
#pragma unroll
        for (int r = 0; r < 4; ++r) {
          const int row = m0 + wm + mi * 16 + fq * 4 + r;
          float v = acc[mi][ni][r] + bias_v;
          if (DO_SELU) v = v > 0.0f ? 1.0507009873554805f * v
                                    : 1.7580993408473766f * (expf(v) - 1.0f);
          long addr;
          if (ADDR_MODE == 0) {
            addr = sCz * z + (long)row * N + col;
          } else {                               // mode 2: z=b*4+h; cat[b,s,h*512+col]
            int b = z >> 2, h = z & 3;
            addr = ((long)(b * 2048 + row)) * 2048 + h * 512 + col;
          }
          if (F32OUT) ((float*)Cout)[addr] = v;
          else        ((bf16*)Cout)[addr] = (bf16)v;
        }
      }
    }
  }
}

// ---------------- launcher ----------------
extern "C" void kernel_launch(void* const* d_in, const int* in_sizes, int n_in,
                              void* d_out, int out_size, void* d_ws, size_t ws_size,
                              hipStream_t stream) {
  (void)in_sizes; (void)n_in; (void)out_size; (void)ws_size;
  const float* x_enc = (const float*)d_in[0];
  const float* x_dec = (const float*)d_in[1];
  const float* Wq = (const float*)d_in[2];
  const float* bq = (const float*)d_in[3];
  const float* Wk = (const float*)d_in[4];
  const float* bk = (const float*)d_in[5];
  const float* Wv = (const float*)d_in[6];
  const float* bv = (const float*)d_in[7];
  const float* Wo = (const float*)d_in[8];
  const float* bo = (const float*)d_in[9];
  const float* g1 = (const float*)d_in[10];
  const float* be1 = (const float*)d_in[11];
  const float* g2 = (const float*)d_in[12];
  const float* be2 = (const float*)d_in[13];
  const float* W1 = (const float*)d_in[14];
  const float* b1 = (const float*)d_in[15];
  const float* W2 = (const float*)d_in[16];
  const float* b2 = (const float*)d_in[17];
  const float* g3 = (const float*)d_in[18];
  const float* be3 = (const float*)d_in[19];

  char* ws = (char*)d_ws;
  const size_t MB = 1u << 20;
  bf16*  Yfold  = (bf16*) (ws + 0);        // [0,8)   dead after Afold GEMM
  float* xd_f   = (float*)(ws + 0);        // [0,16)  LN1 out
  bf16*  Ttrig  = (bf16*) (ws + 16 * MB);  // [16,17)
  bf16*  Yt     = (bf16*) (ws + 17 * MB);  // [17,33) dead after fold
  float* attn_f = (float*)(ws + 17 * MB);  // Wo out, dead after LN2
  float* ff_f   = (float*)(ws + 17 * MB);  // W2 out
  float* xf_f   = (float*)(ws + 33 * MB);  // [33,49) dead after LN1
  float* x2_f   = (float*)(ws + 33 * MB);  // LN2 out
  bf16*  xd_b   = (bf16*) (ws + 49 * MB);  // [49,57)
  bf16*  xdec_b = (bf16*) (ws + 57 * MB);  // [57,65) dead after Yt GEMM
  bf16*  qs     = (bf16*) (ws + 57 * MB);  // [57,89) Q out (after LN1)
  bf16*  midb   = (bf16*) (ws + 89 * MB);  // [89,121) W1 out
  bf16*  Afold  = (bf16*) (ws + 121 * MB); // [121,129) dead after Afold GEMM
  bf16*  gcT    = (bf16*) (ws + 129 * MB); // [129,137)
  bf16*  vsT    = (bf16*) (ws + 137 * MB); // [137,169)
  bf16*  xenc_b = (bf16*) (ws + 169 * MB); // [169,177)
  bf16*  BtQ    = (bf16*) (ws + 177 * MB);
  bf16*  BtK    = (bf16*) (ws + 179 * MB);
  bf16*  WvT    = (bf16*) (ws + 181 * MB);
  bf16*  WoT    = (bf16*) (ws + 183 * MB);
  bf16*  W1T    = (bf16*) (ws + 185 * MB);
  bf16*  W2T    = (bf16*) (ws + 187 * MB);
  bf16*  ksT    = (bf16*) (ws + 193 * MB); // [193,225) dead after gc GEMM
  bf16*  cat    = (bf16*) (ws + 193 * MB); // out-GEMM out
  bf16*  x2_b   = (bf16*) (ws + 225 * MB); // [225,233)

  // --- prep ---
  gen_ttrig<<<2048, 256, 0, stream>>>(Ttrig);
  gen_afold<<<16384, 256, 0, stream>>>(Afold);
  cast_f2b<<<16384, 256, 0, stream>>>(x_dec, xdec_b, 4194304);
  cast_f2b<<<16384, 256, 0, stream>>>(x_enc, xenc_b, 4194304);
  wtrans_all<<<6144, 256, 0, stream>>>(Wq, Wk, Wv, Wo, W1, W2,
                                       BtQ, BtK, WvT, WoT, W1T, W2T);

  // --- Fourier mixing ---
  gemm_bt<128, 0, 0, 0, 0, 0><<<512, 256, 0, stream>>>(
      Ttrig, xdec_b, nullptr, Yt, 2048, 512, 0L, 1048576L, 0L, 2097152L, 16, 8, 0);
  fold_y<<<16384, 256, 0, stream>>>(Yt, Yfold);
  gemm_bt<64, 0, 0, 0, 1, 1><<<512, 256, 0, stream>>>(
      Afold, Yfold, nullptr, xf_f, 512, 2048, 0L, 1048576L, 0L, 1048576L, 8, 16, 32);
  ln_kernel<1, 1><<<8192, 256, 0, stream>>>(x_dec, xf_f, g1, be1, xd_b, xd_f);

  // --- attention ---
  gemm_bt<128, 4, 1, 0, 0, 1><<<1024, 256, 0, stream>>>(   // Q + head-softmax
      xd_b, BtQ, bq, qs, 2048, 512, 0L, 0L, 0L, 0L, 16, 64, 16);
  gemm_bt<128, 5, 1, 0, 0, 1><<<1024, 256, 0, stream>>>(   // K + head-softmax, [B,H,D,S]
      xenc_b, BtK, bk, ksT, 2048, 512, 0L, 0L, 0L, 0L, 16, 64, 16);
  gemm_bt<128, 3, 1, 0, 0, 1><<<1024, 256, 0, stream>>>(   // V, [B,H,D,S]
      xenc_b, WvT, bv, vsT, 512, 512, 0L, 262144L, 512L, 0L, 4, 64, 16);
  gemm_bt<64, 0, 0, 0, 0, 2><<<512, 256, 0, stream>>>(     // gc^T (z=b*4+h, K=2048)
      vsT, ksT, nullptr, gcT, 512, 2048, 1048576L, 1048576L, 0L, 262144L, 8, 4, 32);
  gemm_bt<128, 2, 0, 0, 0, 2><<<1024, 256, 0, stream>>>(   // out = qs.gc -> cat
      qs, gcT, nullptr, cat, 512, 512, 1048576L, 262144L, 0L, 0L, 4, 16, 64);
  gemm_bt<64, 0, 1, 0, 1, 1><<<512, 256, 0, stream>>>(     // attn = cat.WoP + bo
      cat, WoT, bo, attn_f, 512, 2048, 0L, 0L, 0L, 0L, 8, 64, 8);
  ln_kernel<1, 1><<<8192, 256, 0, stream>>>(xd_f, attn_f, g2, be2, x2_b, x2_f);

  // --- FFN ---
  gemm_bt<128, 0, 1, 1, 0, 1><<<1024, 256, 0, stream>>>(
      x2_b, W1T, b1, midb, 2048, 512, 0L, 0L, 0L, 0L, 16, 64, 16);
  gemm_bt<64, 0, 1, 0, 1, 1><<<512, 256, 0, stream>>>(
      midb, W2T, b2, ff_f, 512, 2048, 0L, 0L, 0L, 0L, 8, 64, 8);
  ln_kernel<0, 1><<<8192, 256, 0, stream>>>(x2_f, ff_f, g3, be3, nullptr, (float*)d_out);
}

// Round 4
// 450.682 us; speedup vs baseline: 1.3374x; 1.0314x over previous
//
#include <hip/hip_runtime.h>
#include <stdint.h>

typedef __bf16 bf16;
typedef __bf16 bf16x8 __attribute__((ext_vector_type(8)));
typedef float f32x4 __attribute__((ext_vector_type(4)));

// ---------------- async global->LDS (16B per lane) ----------------
static __device__ __forceinline__ void async16(const void* g, void* l) {
  __builtin_amdgcn_global_load_lds(
      (__attribute__((address_space(1))) void*)g,
      (__attribute__((address_space(3))) void*)l, 16, 0, 0);
}

// ---------------- merged prep: trig tables + casts + all weight transposes ----------------
// blocks [0,2048) ttrig | [2048,18432) afold | [18432,34816) cast x_dec |
// [34816,51200) cast x_enc | [51200,57344) weight transposes.
__global__ void __launch_bounds__(256) prep_all(
    const float* __restrict__ xdec, const float* __restrict__ xenc,
    bf16* __restrict__ Ttrig, bf16* __restrict__ Afold,
    bf16* __restrict__ xdec_b, bf16* __restrict__ xenc_b,
    const float* __restrict__ Wq, const float* __restrict__ Wk,
    const float* __restrict__ Wv, const float* __restrict__ Wo,
    const float* __restrict__ W1, const float* __restrict__ W2,
    bf16* __restrict__ BtQ, bf16* __restrict__ BtK, bf16* __restrict__ WvT,
    bf16* __restrict__ WoT, bf16* __restrict__ W1T, bf16* __restrict__ W2T) {
  __shared__ bf16 tile[32][33];
  int id = blockIdx.x;
  if (id < 2048) {                     // Ttrig[1024][512]
    int idx = id * 256 + threadIdx.x;
    int d = idx & 511, jp = idx >> 9;
    int jj = jp >> 1, p = jp & 1;
    int t = (d * jj) & 511;
    float ang = (float)t * (6.283185307179586f / 512.0f);
    Ttrig[idx] = (bf16)(p ? sinf(ang) : cosf(ang));
  } else if (id < 18432) {             // Afold[2048][2048]
    int idx = (id - 2048) * 256 + threadIdx.x;
    int k = idx & 2047, k1 = idx >> 11;
    int s = (k < 1025) ? k : (k - 1024);
    int t = (k1 * s) & 2047;
    float ang = (float)t * (6.283185307179586f / 2048.0f);
    Afold[idx] = (bf16)((k < 1025) ? cosf(ang) : -sinf(ang));
  } else if (id < 34816) {
    int i = (id - 18432) * 256 + threadIdx.x;
    xdec_b[i] = (bf16)xdec[i];
  } else if (id < 51200) {
    int i = (id - 34816) * 256 + threadIdx.x;
    xenc_b[i] = (bf16)xenc[i];
  } else {
    int id2 = id - 51200;
    int kind = id2 >> 10, t = id2 & 1023;
    const float* in; bf16* out; int R, C, rt, ct;
    bool operm = false, iperm = false;
    if (kind == 0)      { in = Wq; out = BtQ; R = 2048; C = 512; rt = t >> 4; ct = t & 15; iperm = true; }
    else if (kind == 1) { in = Wk; out = BtK; R = 2048; C = 512; rt = t >> 4; ct = t & 15; iperm = true; }
    else if (kind == 2) {
      int zz = t >> 8, tt = t & 255;
      in = Wv + (long)zz * 262144; out = WvT + (long)zz * 262144;
      R = 512; C = 512; rt = tt >> 4; ct = tt & 15;
    }
    else if (kind == 3) { in = Wo; out = WoT; R = 2048; C = 512; rt = t >> 4; ct = t & 15; operm = true; }
    else if (kind == 4) { in = W1; out = W1T; R = 512; C = 2048; rt = t >> 6; ct = t & 63; }
    else                { in = W2; out = W2T; R = 2048; C = 512; rt = t >> 4; ct = t & 15; }
    int c0 = ct * 32, r0 = rt * 32;
    int tx = threadIdx.x & 31, ty = threadIdx.x >> 5;
#pragma unroll
    for (int i = 0; i < 32; i += 8) {
      int r = r0 + ty + i;
      int rr = operm ? (((r & 511) << 2) | (r >> 9)) : r;   // Wo: k'=h*512+e <- row e*4+h
      tile[ty + i][tx] = (bf16)in[(long)rr * C + (c0 + tx)];
    }
    __syncthreads();
#pragma unroll
    for (int i = 0; i < 32; i += 8) {
      int cc = c0 + ty + i, rr = r0 + tx;
      if (iperm)   // Bt row n = 4e+h from Wq/Wk row h*512+din
        out[((long)(4 * cc + (rr >> 9)) << 9) + (rr & 511)] = tile[tx][ty + i];
      else
        out[(long)cc * R + rr] = tile[tx][ty + i];
    }
  }
}

// Fold Yt [4][512][4096] (k = p*2048+s) -> Yf [4][512][2048] via s <-> 2048-s symmetry.
__global__ void __launch_bounds__(256) fold_y(const bf16* __restrict__ Yt,
                                              bf16* __restrict__ Yf) {
  int idx = blockIdx.x * 256 + threadIdx.x;
  int k = idx & 2047;
  int j = (idx >> 11) & 511;
  int b = idx >> 20;
  const bf16* yin = Yt + (long)b * 2097152 + (long)j * 4096;
  float v;
  if (k < 1025) {
    if (k == 0) v = (float)yin[0];
    else if (k == 1024) v = (float)yin[1024];
    else v = (float)yin[k] + (float)yin[2048 - k];
  } else {
    int s = k - 1024;
    v = (float)yin[2048 + s] - (float)yin[2048 + 2048 - s];
  }
  Yf[(long)b * 1048576 + (long)j * 2048 + k] = (bf16)v;
}

// ---------------- head softmax pass ----------------
// blocks [0,16384): Q -> qs[b,h,s,e] (coalesced 4-stream writes)
// blocks [16384,17408): K -> ksT[b,h,d,s] via XOR-swizzled LDS 64x64 tile transpose
__global__ void __launch_bounds__(256) softmax_qk(
    const bf16* __restrict__ qlog, bf16* __restrict__ qs,
    const bf16* __restrict__ klog, bf16* __restrict__ ksT) {
  __shared__ bf16 lds[4 * 64 * 64];   // [h][e][swizzled s]
  const int bid = blockIdx.x, t = threadIdx.x;
  if (bid < 16384) {
    int idx = bid * 256 + t;
    int e = idx & 511, s = (idx >> 9) & 2047, b = idx >> 20;
    bf16 raw[4] __attribute__((aligned(8)));
    *(uint2*)raw = *(const uint2*)(qlog + ((long)(b * 2048 + s) * 2048 + 4 * e));
    float v0 = (float)raw[0], v1 = (float)raw[1], v2 = (float)raw[2], v3 = (float)raw[3];
    float m = fmaxf(fmaxf(v0, v1), fmaxf(v2, v3));
    float e0 = expf(v0 - m), e1 = expf(v1 - m), e2 = expf(v2 - m), e3 = expf(v3 - m);
    float rs = 1.0f / (e0 + e1 + e2 + e3);
    long base = ((long)(b * 4) * 2048 + s) * 512 + e;   // h stride = 1048576
    qs[base] = (bf16)(e0 * rs);
    qs[base + 1048576] = (bf16)(e1 * rs);
    qs[base + 2097152] = (bf16)(e2 * rs);
    qs[base + 3145728] = (bf16)(e3 * rs);
  } else {
    int tb = bid - 16384;            // 4b x 32 s-tiles x 8 e-tiles
    int b = tb >> 8, rem = tb & 255;
    int s0 = (rem >> 3) << 6, e0 = (rem & 7) << 6;
    int te = t & 63, tr = t >> 6;
#pragma unroll
    for (int i = 0; i < 16; ++i) {
      int s = tr + (i << 2);
      bf16 raw[4] __attribute__((aligned(8)));
      *(uint2*)raw = *(const uint2*)(klog + ((long)(b * 2048 + s0 + s) * 2048 + 4 * (e0 + te)));
      float v0 = (float)raw[0], v1 = (float)raw[1], v2 = (float)raw[2], v3 = (float)raw[3];
      float m = fmaxf(fmaxf(v0, v1), fmaxf(v2, v3));
      float x0 = expf(v0 - m), x1 = expf(v1 - m), x2 = expf(v2 - m), x3 = expf(v3 - m);
      float rs = 1.0f / (x0 + x1 + x2 + x3);
      int cp = ((((s >> 2) ^ (te & 15)) << 2) | (s & 3));
      int base = te * 64 + cp;
      lds[base] = (bf16)(x0 * rs);
      lds[4096 + base] = (bf16)(x1 * rs);
      lds[8192 + base] = (bf16)(x2 * rs);
      lds[12288 + base] = (bf16)(x3 * rs);
    }
    __syncthreads();
    int sc = t & 15, r = t >> 4;
#pragma unroll
    for (int i = 0; i < 16; ++i) {
      int he = r + (i << 4);         // 0..255
      int h = he >> 6, e = he & 63;
      int cp = (sc ^ (e & 15)) << 2;
      bf16 tmp[4] __attribute__((aligned(8)));
      *(uint2*)tmp = *(const uint2*)&lds[h * 4096 + e * 64 + cp];
      *(uint2*)(ksT + ((long)(b * 4 + h) * 512 + e0 + e) * 2048 + s0 + (sc << 2)) =
          *(const uint2*)tmp;
    }
  }
}

// ---------------- LayerNorm over D=512: out = g*(A+B - mu)*rstd + be ----------------
template <int WRITE_BF16, int WRITE_F32>
__global__ void __launch_bounds__(256) ln_kernel(
    const float* __restrict__ A, const float* __restrict__ Bv,
    const float* __restrict__ g, const float* __restrict__ be,
    bf16* __restrict__ outb, float* __restrict__ outf) {
  const int row = blockIdx.x, t = threadIdx.x;
  const long base = (long)row * 512;
  float v0 = A[base + t] + Bv[base + t];
  float v1 = A[base + t + 256] + Bv[base + t + 256];
  float s = v0 + v1, q = v0 * v0 + v1 * v1;
#pragma unroll
  for (int off = 32; off > 0; off >>= 1) {
    s += __shfl_down(s, off);
    q += __shfl_down(q, off);
  }
  __shared__ float red[8];
  const int wv = t >> 6, ln = t & 63;
  if (ln == 0) { red[wv] = s; red[wv + 4] = q; }
  __syncthreads();
  float S = red[0] + red[1] + red[2] + red[3];
  float Q = red[4] + red[5] + red[6] + red[7];
  float mu = S * (1.0f / 512.0f);
  float var = Q * (1.0f / 512.0f) - mu * mu;
  float rstd = rsqrtf(var + 1e-5f);
  float o0 = g[t] * (v0 - mu) * rstd + be[t];
  float o1 = g[t + 256] * (v1 - mu) * rstd + be[t + 256];
  if (WRITE_BF16) { outb[base + t] = (bf16)o0; outb[base + t + 256] = (bf16)o1; }
  if (WRITE_F32)  { outf[base + t] = o0; outf[base + t + 256] = o1; }
}

// ---------------- GEMM: C = A[M,K] * Bt[N,K]^T, 1D grid with XCD-group swizzle ---------
// SWIZ: 0 plain; 1 group-by-y (flat%8==y%8); 2 group-by-z. gin = blocks per group.
// ADDR_MODE: 0 plain (sCz*z); 2 attn out to cat[b,s,h*512+col] (z=b*4+h);
// 3 V transposed scatter to [B,H,D,S] (z=head, 8B packed).
// HAS_BIAS: 0 none, 1 bias[sBiasz*z+col], 2 head-interleaved bias[(col&3)*512+(col>>2)].
template <int BN, int ADDR_MODE, int HAS_BIAS, int DO_SELU, int F32OUT, int SWIZ>
__global__ void __launch_bounds__(256, 2) gemm_bt(
    const bf16* __restrict__ A, const bf16* __restrict__ Bt,
    const float* __restrict__ bias, void* __restrict__ Cout,
    int N, int K, long sAz, long sBz, long sBiasz, long sCz,
    int gx, int gy, int gin) {
  __shared__ __align__(16) bf16 lA[128 * 64];
  __shared__ __align__(16) bf16 lB[BN * 64];
  int x, y, z;
  {
    int id = blockIdx.x;
    if (SWIZ == 0) {
      x = id % gx; int t2 = id / gx; y = t2 % gy; z = t2 / gy;
    } else {
      int xcd = id & 7, r = id >> 3;
      int inner = r % gin, G = xcd + 8 * (r / gin);
      if (SWIZ == 1) { y = G; x = inner % gx; z = inner / gx; }
      else           { z = G; x = inner % gx; y = inner / gx; }
    }
  }
  A  += sAz * z;
  Bt += sBz * z;
  const int m0 = y * 128, n0 = x * BN;
  const int t = threadIdx.x;
  const int lane = t & 63, wave = t >> 6;
  const int srow = t >> 3;
  const int pch  = t & 7;
  const int lch  = pch ^ (srow & 7);   // XOR bank swizzle (global-side)
  const bf16* Ag = A  + (long)(m0 + srow) * K + lch * 8;
  const bf16* Bg = Bt + (long)(n0 + srow) * K + lch * 8;
  bf16* lAp = lA + srow * 64 + pch * 8;
  bf16* lBp = lB + srow * 64 + pch * 8;
  constexpr int MI = (BN == 128) ? 4 : 2;
  const int wm = (BN == 128) ? (wave >> 1) * 64 : wave * 32;
  const int wn = (BN == 128) ? (wave & 1) * 64 : 0;
  const int fr = lane & 15, fq = lane >> 4;

  f32x4 acc[MI][4] = {};

  for (int k0 = 0; k0 < K; k0 += 64) {
    __syncthreads();
#pragma unroll
    for (int i = 0; i < 4; ++i)
      async16(Ag + k0 + (long)(32 * i) * K, lAp + 32 * i * 64);
#pragma unroll
    for (int i = 0; i < BN / 32; ++i)
      async16(Bg + k0 + (long)(32 * i) * K, lBp + 32 * i * 64);
    __syncthreads();
#pragma unroll
    for (int kk = 0; kk < 2; ++kk) {
      bf16x8 av[MI], bfrag[4];
#pragma unroll
      for (int mi = 0; mi < MI; ++mi) {
        int r = wm + mi * 16 + fr;
        int c = (kk * 4 + fq) ^ (r & 7);
        av[mi] = *(const bf16x8*)&lA[r * 64 + c * 8];
      }
#pragma unroll
      for (int ni = 0; ni < 4; ++ni) {
        int r = wn + ni * 16 + fr;
        int c = (kk * 4 + fq) ^ (r & 7);
        bfrag[ni] = *(const bf16x8*)&lB[r * 64 + c * 8];
      }
#pragma unroll
      for (int mi = 0; mi < MI; ++mi)
#pragma unroll
        for (int ni = 0; ni < 4; ++ni)
          acc[mi][ni] = __builtin_amdgcn_mfma_f32_16x16x32_bf16(
              av[mi], bfrag[ni], acc[mi][ni], 0, 0, 0);
    }
  }

  // epilogue: C/D layout col = lane&15, row = (lane>>4)*4 + reg
#pragma unroll
  for (int mi = 0; mi < MI; ++mi) {
#pragma unroll
    for (int ni = 0; ni < 4; ++ni) {
      const int col = n0 + wn + ni * 16 + fr;
      float bias_v = 0.0f;
      if (HAS_BIAS == 1) bias_v = bias[sBiasz * z + col];
      if (HAS_BIAS == 2) bias_v = bias[(col & 3) * 512 + (col >> 2)];
      if (ADDR_MODE == 3) {
        const int row0 = m0 + wm + mi * 16 + fq * 4;
        const int b = row0 >> 11, s = row0 & 2047;
        bf16 tmp[4] __attribute__((aligned(8)));
#pragma unroll
        for (int r = 0; r < 4; ++r) tmp[r] = (bf16)(acc[mi][ni][r] + bias_v);
        long addr = ((long)((b << 2) + z) * 512 + col) * 2048 + s;
        *(uint2*)((bf16*)Cout + addr) = *(const uint2*)tmp;
      } else {
#pragma unroll
        for (int r = 0; r < 4; ++r) {
          const int row = m0 + wm + mi * 16 + fq * 4 + r;
          float v = acc[mi][ni][r] + bias_v;
          if (DO_SELU) v = v > 0.0f ? 1.0507009873554805f * v
                                    : 1.7580993408473766f * (expf(v) - 1.0f);
          long addr;
          if (ADDR_MODE == 0) {
            addr = sCz * z + (long)row * N + col;
          } else {                               // mode 2: z=b*4+h; cat[b,s,h*512+col]
            int b = z >> 2, h = z & 3;
            addr = ((long)(b * 2048 + row)) * 2048 + h * 512 + col;
          }
          if (F32OUT) ((float*)Cout)[addr] = v;
          else        ((bf16*)Cout)[addr] = (bf16)v;
        }
      }
    }
  }
}

// ---------------- launcher ----------------
extern "C" void kernel_launch(void* const* d_in, const int* in_sizes, int n_in,
                              void* d_out, int out_size, void* d_ws, size_t ws_size,
                              hipStream_t stream) {
  (void)in_sizes; (void)n_in; (void)out_size; (void)ws_size;
  const float* x_enc = (const float*)d_in[0];
  const float* x_dec = (const float*)d_in[1];
  const float* Wq = (const float*)d_in[2];
  const float* bq = (const float*)d_in[3];
  const float* Wk = (const float*)d_in[4];
  const float* bk = (const float*)d_in[5];
  const float* Wv = (const float*)d_in[6];
  const float* bv = (const float*)d_in[7];
  const float* Wo = (const float*)d_in[8];
  const float* bo = (const float*)d_in[9];
  const float* g1 = (const float*)d_in[10];
  const float* be1 = (const float*)d_in[11];
  const float* g2 = (const float*)d_in[12];
  const float* be2 = (const float*)d_in[13];
  const float* W1 = (const float*)d_in[14];
  const float* b1 = (const float*)d_in[15];
  const float* W2 = (const float*)d_in[16];
  const float* b2 = (const float*)d_in[17];
  const float* g3 = (const float*)d_in[18];
  const float* be3 = (const float*)d_in[19];

  char* ws = (char*)d_ws;
  const size_t MB = 1u << 20;
  // time-disjoint aliasing, peak 229 MiB
  bf16*  qlog   = (bf16*) (ws + 0);        // Q logits -> dead after softmax
  bf16*  cat    = (bf16*) (ws + 0);        // out-GEMM out
  bf16*  klog   = (bf16*) (ws + 32 * MB);  // K logits -> dead after softmax
  bf16*  midb   = (bf16*) (ws + 32 * MB);  // W1 out
  bf16*  qs     = (bf16*) (ws + 64 * MB);  // softmax Q -> dead after out-GEMM
  float* ff_f   = (float*)(ws + 64 * MB);  // W2 out
  bf16*  ksT    = (bf16*) (ws + 96 * MB);  // softmax K -> dead after gc-GEMM
  float* attn_f = (float*)(ws + 96 * MB);  // Wo out
  bf16*  vsT    = (bf16*) (ws + 128 * MB); // V out -> dead after gc-GEMM
  float* x2_f   = (float*)(ws + 128 * MB); // LN2 out (fp32)
  bf16*  x2_b   = (bf16*) (ws + 144 * MB); // LN2 out (bf16)
  float* xd_f   = (float*)(ws + 160 * MB); // LN1 out (fp32)
  bf16*  Yt     = (bf16*) (ws + 176 * MB); // stage-1 DFT -> dead after fold
  float* xf_f   = (float*)(ws + 176 * MB); // Afold out -> dead after LN1
  bf16*  xdec_b = (bf16*) (ws + 192 * MB); // dead after Yt GEMM
  bf16*  Yfold  = (bf16*) (ws + 192 * MB); // fold out -> dead after Afold GEMM
  bf16*  xd_b   = (bf16*) (ws + 192 * MB); // LN1 bf16 -> dead after Q GEMM
  bf16*  gcT    = (bf16*) (ws + 192 * MB); // gc out -> dead after out GEMM
  bf16*  xenc_b = (bf16*) (ws + 200 * MB);
  bf16*  Ttrig  = (bf16*) (ws + 208 * MB);
  bf16*  Afold  = (bf16*) (ws + 209 * MB);
  bf16*  BtQ    = (bf16*) (ws + 217 * MB);
  bf16*  BtK    = (bf16*) (ws + 219 * MB);
  bf16*  WvT    = (bf16*) (ws + 221 * MB);
  bf16*  WoT    = (bf16*) (ws + 223 * MB);
  bf16*  W1T    = (bf16*) (ws + 225 * MB);
  bf16*  W2T    = (bf16*) (ws + 227 * MB); // end 229 MiB

  // --- prep (one launch) ---
  prep_all<<<57344, 256, 0, stream>>>(x_dec, x_enc, Ttrig, Afold, xdec_b, xenc_b,
                                      Wq, Wk, Wv, Wo, W1, W2,
                                      BtQ, BtK, WvT, WoT, W1T, W2T);

  // --- Fourier mixing ---
  gemm_bt<128, 0, 0, 0, 0, 0><<<512, 256, 0, stream>>>(
      Ttrig, xdec_b, nullptr, Yt, 2048, 512, 0L, 1048576L, 0L, 2097152L, 16, 8, 0);
  fold_y<<<16384, 256, 0, stream>>>(Yt, Yfold);
  gemm_bt<64, 0, 0, 0, 1, 1><<<512, 256, 0, stream>>>(
      Afold, Yfold, nullptr, xf_f, 512, 2048, 0L, 1048576L, 0L, 1048576L, 8, 16, 32);
  ln_kernel<1, 1><<<8192, 256, 0, stream>>>(x_dec, xf_f, g1, be1, xd_b, xd_f);

  // --- attention ---
  gemm_bt<128, 0, 2, 0, 0, 1><<<1024, 256, 0, stream>>>(   // Q logits [b,s,4e+h]
      xd_b, BtQ, bq, qlog, 2048, 512, 0L, 0L, 0L, 0L, 16, 64, 16);
  gemm_bt<128, 0, 2, 0, 0, 1><<<1024, 256, 0, stream>>>(   // K logits [b,s,4e+h]
      xenc_b, BtK, bk, klog, 2048, 512, 0L, 0L, 0L, 0L, 16, 64, 16);
  gemm_bt<128, 3, 1, 0, 0, 1><<<1024, 256, 0, stream>>>(   // V -> [B,H,D,S]
      xenc_b, WvT, bv, vsT, 512, 512, 0L, 262144L, 512L, 0L, 4, 64, 16);
  softmax_qk<<<17408, 256, 0, stream>>>(qlog, qs, klog, ksT);
  gemm_bt<64, 0, 0, 0, 0, 2><<<512, 256, 0, stream>>>(     // gc^T (z=b*4+h, K=2048)
      vsT, ksT, nullptr, gcT, 512, 2048, 1048576L, 1048576L, 0L, 262144L, 8, 4, 32);
  gemm_bt<128, 2, 0, 0, 0, 2><<<1024, 256, 0, stream>>>(   // out = qs.gc -> cat
      qs, gcT, nullptr, cat, 512, 512, 1048576L, 262144L, 0L, 0L, 4, 16, 64);
  gemm_bt<64, 0, 1, 0, 1, 1><<<512, 256, 0, stream>>>(     // attn = cat.WoP + bo
      cat, WoT, bo, attn_f, 512, 2048, 0L, 0L, 0L, 0L, 8, 64, 8);
  ln_kernel<1, 1><<<8192, 256, 0, stream>>>(xd_f, attn_f, g2, be2, x2_b, x2_f);

  // --- FFN ---
  gemm_bt<128, 0, 1, 1, 0, 1><<<1024, 256, 0, stream>>>(
      x2_b, W1T, b1, midb, 2048, 512, 0L, 0L, 0L, 0L, 16, 64, 16);
  gemm_bt<64, 0, 1, 0, 1, 1><<<512, 256, 0, stream>>>(
      midb, W2T, b2, ff_f, 512, 2048, 0L, 0L, 0L, 0L, 8, 64, 8);
  ln_kernel<0, 1><<<8192, 256, 0, stream>>>(x2_f, ff_f, g3, be3, nullptr, (float*)d_out);
}